// Round 3
// baseline (1130.513 us; speedup 1.0000x reference)
//
#include <hip/hip_runtime.h>
#include <hip/hip_bf16.h>

#define B_SZ  32768
#define S_MC  4
#define D_IN  256
#define LAT   8
#define NBINS 300
#define KDIM  1323
#define RNK   4

constexpr int TPB = 256;
constexpr int KPT = (KDIM + TPB - 1) / TPB;  // 6

__global__ __launch_bounds__(TPB) void cp_profile_kernel(
    const float* __restrict__ x,       // (B, 256)
    const float* __restrict__ eps,     // (S, B, 8)
    const float* __restrict__ A,       // (300, 4)
    const float* __restrict__ Bm,      // (1323, 4)
    const float* __restrict__ C,       // (8, 4)
    const float* __restrict__ bias,    // (300, 1323)
    const float* __restrict__ mu_w,    // (8, 256)
    const float* __restrict__ mu_b,    // (8,)
    const float* __restrict__ std_w,   // (8, 256)
    const float* __restrict__ std_b,   // (8,)
    const int*   __restrict__ glab,    // (B,)
    float* __restrict__ out)
{
    __shared__ float  x_s[D_IN];
    __shared__ float4 B_s[KDIM];
    __shared__ float  bn_s[KDIM];
    __shared__ float  muh_s[LAT];
    __shared__ float  stdh_s[LAT];
    __shared__ float  w_s[5][RNK];
    __shared__ float  red_s[4];

    const int b    = blockIdx.x;
    const int tid  = threadIdx.x;
    const int lane = tid & 63;
    const int wid  = tid >> 6;
    const int g    = glab[b];

    // ---- stage x row, B matrix (float4/k), gathered bias row ----
    x_s[tid] = x[b * D_IN + tid];
    const float4* B4 = reinterpret_cast<const float4*>(Bm);
    for (int k = tid; k < KDIM; k += TPB) {
        B_s[k]  = B4[k];
        bn_s[k] = bias[(size_t)g * KDIM + k];
    }
    __syncthreads();

    // ---- 16 dot products (8 mu pre-act, 8 std pre-act), 4 per wave ----
    #pragma unroll
    for (int dd = 0; dd < 4; ++dd) {
        const int d = wid * 4 + dd;
        const float* W = (d < LAT) ? (mu_w + d * D_IN) : (std_w + (d - LAT) * D_IN);
        float acc = 0.f;
        #pragma unroll
        for (int i = 0; i < D_IN / 64; ++i)
            acc += x_s[lane + 64 * i] * W[lane + 64 * i];
        #pragma unroll
        for (int off = 32; off > 0; off >>= 1)
            acc += __shfl_xor(acc, off, 64);
        if (lane == 0) {
            if (d < LAT) {
                muh_s[d] = acc + mu_b[d];
            } else {
                const float y = acc + std_b[d - LAT];
                stdh_s[d - LAT] = fmaxf(y, 0.f) + log1pf(expf(-fabsf(y)));
            }
        }
    }
    __syncthreads();

    // ---- per-pass CP weights: w[s][r] = A_n[r] * z[s][r]; s=4 is mean path ----
    if (tid < 20) {
        const int s = tid >> 2, r = tid & 3;
        float z = 0.f;
        #pragma unroll
        for (int j = 0; j < LAT; ++j) {
            float h = muh_s[j];
            if (s < S_MC) h += stdh_s[j] * eps[((size_t)s * B_SZ + b) * LAT + j];
            z += h * C[j * RNK + r];
        }
        w_s[s][r] = A[g * RNK + r] * z;
    }
    // ---- write mu_h / std_h outputs (fp32) ----
    const size_t base_small = (size_t)5 * B_SZ * KDIM;
    if (tid >= 32 && tid < 40)
        out[base_small + (size_t)b * LAT + (tid - 32)] = muh_s[tid - 32];
    if (tid >= 40 && tid < 48)
        out[base_small + (size_t)B_SZ * LAT + (size_t)b * LAT + (tid - 40)] = stdh_s[tid - 40];
    __syncthreads();

    // ---- 5 softmax passes (4 samples + mean) ----
    for (int s = 0; s < 5; ++s) {
        const float w0 = w_s[s][0], w1 = w_s[s][1], w2 = w_s[s][2], w3 = w_s[s][3];
        float lg[KPT];
        float lmax = -INFINITY;
        #pragma unroll
        for (int i = 0; i < KPT; ++i) {
            const int k = tid + i * TPB;
            if (k < KDIM) {
                const float4 bb = B_s[k];
                const float v = fmaf(w0, bb.x, fmaf(w1, bb.y, fmaf(w2, bb.z, w3 * bb.w))) + bn_s[k];
                lg[i] = v;
                lmax = fmaxf(lmax, v);
            } else {
                lg[i] = -INFINITY;
            }
        }
        #pragma unroll
        for (int off = 32; off > 0; off >>= 1)
            lmax = fmaxf(lmax, __shfl_xor(lmax, off, 64));
        __syncthreads();               // protect red_s reuse from previous reduction
        if (lane == 0) red_s[wid] = lmax;
        __syncthreads();
        lmax = fmaxf(fmaxf(red_s[0], red_s[1]), fmaxf(red_s[2], red_s[3]));

        float lsum = 0.f;
        #pragma unroll
        for (int i = 0; i < KPT; ++i) {
            const float e = __expf(lg[i] - lmax);   // exp(-inf)=0 for padded k
            lg[i] = e;
            lsum += e;
        }
        #pragma unroll
        for (int off = 32; off > 0; off >>= 1)
            lsum += __shfl_xor(lsum, off, 64);
        __syncthreads();
        if (lane == 0) red_s[wid] = lsum;
        __syncthreads();
        lsum = red_s[0] + red_s[1] + red_s[2] + red_s[3];
        const float inv = 1.f / lsum;

        const size_t obase = (s < S_MC)
            ? ((size_t)(s * B_SZ + b) * KDIM)
            : ((size_t)S_MC * B_SZ * KDIM + (size_t)b * KDIM);
        #pragma unroll
        for (int i = 0; i < KPT; ++i) {
            const int k = tid + i * TPB;
            if (k < KDIM) out[obase + k] = lg[i] * inv;
        }
    }
}

extern "C" void kernel_launch(void* const* d_in, const int* in_sizes, int n_in,
                              void* d_out, int out_size, void* d_ws, size_t ws_size,
                              hipStream_t stream) {
    const float* x     = (const float*)d_in[0];
    const float* eps   = (const float*)d_in[1];
    const float* A     = (const float*)d_in[2];
    const float* Bm    = (const float*)d_in[3];
    const float* C     = (const float*)d_in[4];
    const float* bias  = (const float*)d_in[5];
    const float* mu_w  = (const float*)d_in[6];
    const float* mu_b  = (const float*)d_in[7];
    const float* std_w = (const float*)d_in[8];
    const float* std_b = (const float*)d_in[9];
    const int*   glab  = (const int*)d_in[10];
    float* out = (float*)d_out;

    cp_profile_kernel<<<B_SZ, TPB, 0, stream>>>(
        x, eps, A, Bm, C, bias, mu_w, mu_b, std_w, std_b, glab, out);
}